// Round 14
// baseline (825.216 us; speedup 1.0000x reference)
//
#include <hip/hip_runtime.h>
#include <hip/hip_bf16.h>

#define TT 8192
#define DD 1024
#define HH 4096
#define EE 8

typedef unsigned short u16;
typedef unsigned int u32;
typedef float fx4 __attribute__((ext_vector_type(4)));
typedef short s8v __attribute__((ext_vector_type(8)));
typedef int i4v __attribute__((ext_vector_type(4)));
typedef u16 u16x4 __attribute__((ext_vector_type(4)));

__device__ __forceinline__ u16 f2bf(float x) {
  union { float f; u32 u; } c; c.f = x;
  u32 r = (c.u + 0x7FFFu + ((c.u >> 16) & 1u)) >> 16;
  return (u16)r;
}

__device__ __forceinline__ void gl2lds16(const void* g, void* l) {
  __builtin_amdgcn_global_load_lds(
      (const __attribute__((address_space(1))) void*)g,
      (__attribute__((address_space(3))) void*)l, 16, 0, 0);
}

// ---------------- meta ----------------
__global__ void zero_meta(int* counts) {
  if (threadIdx.x < EE) counts[threadIdx.x] = 0;
}

// ---------------- transpose + convert W [E][R][C] f32 -> Wt [E][C][R] bf16 ----------------
template<int R, int C>
__global__ void transpose_convert(const float* __restrict__ W, u16* __restrict__ Wt) {
  __shared__ float tile[64][65];
  const int e = blockIdx.z;
  const float* We = W + (size_t)e * R * C;
  u16* Wte = Wt + (size_t)e * R * C;
  const int r0 = blockIdx.y * 64, c0 = blockIdx.x * 64;
  const int tid = threadIdx.x;
  const int a = tid >> 4, b4 = (tid & 15) * 4;
#pragma unroll
  for (int i = 0; i < 4; ++i) {
    int rr = a + i * 16;
    float4 v = *(const float4*)(We + (size_t)(r0 + rr) * C + c0 + b4);
    tile[rr][b4 + 0] = v.x; tile[rr][b4 + 1] = v.y;
    tile[rr][b4 + 2] = v.z; tile[rr][b4 + 3] = v.w;
  }
  __syncthreads();
#pragma unroll
  for (int i = 0; i < 4; ++i) {
    int cc = a + i * 16;
    u16x4 o;
    o[0] = f2bf(tile[b4 + 0][cc]);
    o[1] = f2bf(tile[b4 + 1][cc]);
    o[2] = f2bf(tile[b4 + 2][cc]);
    o[3] = f2bf(tile[b4 + 3][cc]);
    *(u16x4*)(Wte + (size_t)(c0 + cc) * R + r0 + b4) = o;
  }
}

// ---------------- router: logits (f64 acc) + top2 + softmax + histogram + x->bf16 ----------------
__global__ void router_kernel(const float* __restrict__ x, const float* __restrict__ Wg,
                              int* __restrict__ topIdx, float* __restrict__ gates,
                              int* __restrict__ counts, u16* __restrict__ xb) {
  __shared__ float wg[EE][DD + 1];
  const int tid = threadIdx.x;
  for (int i = tid; i < DD * EE; i += 256) wg[i & 7][i >> 3] = Wg[i];
  __syncthreads();
  const int w = tid >> 6, lane = tid & 63;
  const int t = blockIdx.x * 4 + w;
  double acc[EE];
#pragma unroll
  for (int e = 0; e < EE; ++e) acc[e] = 0.0;
  const float* xr = x + (size_t)t * DD;
  u16* xbr = xb + (size_t)t * DD;
  for (int i = 0; i < DD / 64; ++i) {
    int d = i * 64 + lane;
    float xf = xr[d];
    xbr[d] = f2bf(xf);
    double xv = (double)xf;
#pragma unroll
    for (int e = 0; e < EE; ++e) acc[e] += xv * (double)wg[e][d];
  }
#pragma unroll
  for (int e = 0; e < EE; ++e) {
    double v = acc[e];
#pragma unroll
    for (int s = 32; s > 0; s >>= 1) v += __shfl_xor(v, s, 64);
    acc[e] = v;
  }
  if (lane == 0) {
    float v0 = -3.4e38f, v1 = -3.4e38f; int i0 = 0, i1 = 0;
#pragma unroll
    for (int e = 0; e < EE; ++e) {
      float v = (float)acc[e];
      if (v > v0) { v1 = v0; i1 = i0; v0 = v; i0 = e; }
      else if (v > v1) { v1 = v; i1 = e; }
    }
    float ee = expf(v1 - v0);
    float g0 = 1.f / (1.f + ee);
    float g1 = ee / (1.f + ee);
    topIdx[t * 2 + 0] = i0; topIdx[t * 2 + 1] = i1;
    gates[t * 2 + 0] = g0; gates[t * 2 + 1] = g1;
    atomicAdd(&counts[i0], 1);
    atomicAdd(&counts[i1], 1);
  }
}

__global__ void prefix_kernel(const int* __restrict__ counts, int* __restrict__ offsets) {
  if (threadIdx.x == 0) {
    int s = 0;
    for (int e = 0; e < EE; ++e) { offsets[e] = s; s += counts[e]; }
    offsets[EE] = s;
  }
}

// ---------------- deterministic scatter: one block per expert, token-ordered
// (ordering keeps per-expert A-gather rows ascending -> L3 locality in gemm1) ----
__global__ void scatter_det(const int* __restrict__ topIdx, const float* __restrict__ gates,
                            const int* __restrict__ offsets, int* __restrict__ entryTok,
                            float* __restrict__ entryGate) {
  const int e = blockIdx.x;
  const int tid = threadIdx.x;
  const int lane = tid & 63, w = tid >> 6;
  __shared__ int base;
  __shared__ int wsum[16];
  __shared__ int woff[16];
  __shared__ int chunktot;
  if (tid == 0) base = offsets[e];
  __syncthreads();
  for (int t0 = 0; t0 < TT; t0 += 1024) {
    int t = t0 + tid;
    int k = -1;
    if (topIdx[t * 2 + 0] == e) k = 0;
    else if (topIdx[t * 2 + 1] == e) k = 1;
    unsigned long long m = __ballot(k >= 0);
    int pre = __popcll(m & ((1ULL << lane) - 1ULL));
    if (lane == 0) wsum[w] = __popcll(m);
    __syncthreads();
    if (tid == 0) {
      int s = 0;
      for (int i = 0; i < 16; ++i) { woff[i] = s; s += wsum[i]; }
      chunktot = s;
    }
    __syncthreads();
    if (k >= 0) {
      int p = base + woff[w] + pre;
      entryTok[p] = t;
      entryGate[p] = gates[t * 2 + k];
    }
    __syncthreads();
    if (tid == 0) base += chunktot;
    __syncthreads();
  }
}

// ======== GEMM1: h = relu(x_gathered * W1t^T + b1). 256x256 tile, BK=64,
// 16 waves (4m x 4n of 64x64 -> acc[4][4]=64/wave, same per-wave footprint as R12),
// 64KB LDS single-buf (2 blocks/CU), R4-proven 2-barrier loop, T2 source-side
// swizzle, XCD-chunked (e,nx,my-fastest) 1D grid. Staged bytes: 1.07 GB
// (bytes/out ~ 1/256+1/256; the ~6.4 TB/s staging wall is the binding constraint).
template<int K, int N>
__global__ __launch_bounds__(1024) void moe_gemm1(
    const u16* __restrict__ A, const u16* __restrict__ Bt,
    const float* __restrict__ bias,
    const int* __restrict__ counts, const int* __restrict__ offsets,
    const int* __restrict__ entryTok, u16* __restrict__ hout) {
  constexpr int NM = TT / 256;          // 32
  constexpr int NX = N / 256;           // 16
  constexpr int nwg = EE * NX * NM;     // 4096

  const int p = blockIdx.x;
  const int l = (p & 7) * (nwg >> 3) + (p >> 3);
  const int e = l / (NX * NM);
  const int lr = l % (NX * NM);
  const int nx = lr / NM;
  const int my = lr % NM;

  const int cnt = counts[e];
  const int mbase = my * 256;
  if (mbase >= cnt) return;
  const int off = offsets[e];
  const int nbase = nx * 256;
  const int tid = threadIdx.x;
  const int w = tid >> 6, lane = tid & 63;

  __shared__ __align__(16) u16 Asm[256][64];
  __shared__ __align__(16) u16 Bsm[256][64];

  // 2048 16B chunks per operand; 1024 threads -> 2 chunks/thread each.
  // chunk c: row=c>>3, lds_slot=c&7, src slot = (c&7)^(row&7)  (T2 source-side)
  const u16* asrc[2];
  const u16* bsrc[2];
  u32 adst[2], bdst[2];
#pragma unroll
  for (int j = 0; j < 2; ++j) {
    int c = j * 1024 + tid;
    int row = c >> 3;
    int col = ((c & 7) ^ (row & 7)) * 8;
    int gm = mbase + row;
    int mm = (gm < cnt) ? gm : (cnt - 1);
    asrc[j] = A + (size_t)entryTok[off + mm] * K + col;
    adst[j] = (u32)c * 16;
    bsrc[j] = Bt + (size_t)e * N * K + (size_t)(nbase + row) * K + col;
    bdst[j] = (u32)c * 16;
  }

  const int wm = (w >> 2) * 64, wn = (w & 3) * 64;   // 4m x 4n waves
  const int fl = lane & 15, fh = lane >> 4;
  const int fswz = fl & 7;

  fx4 acc[4][4];
#pragma unroll
  for (int mi = 0; mi < 4; ++mi)
#pragma unroll
    for (int ni = 0; ni < 4; ++ni)
      acc[mi][ni] = (fx4){0.f, 0.f, 0.f, 0.f};

  for (int kt = 0; kt < K; kt += 64) {
#pragma unroll
    for (int j = 0; j < 2; ++j) {
      gl2lds16(asrc[j] + kt, (char*)&Asm[0][0] + adst[j]);
      gl2lds16(bsrc[j] + kt, (char*)&Bsm[0][0] + bdst[j]);
    }
    __syncthreads();
#pragma unroll
    for (int ks = 0; ks < 2; ++ks) {
      const int slot = ((ks * 4 + fh) ^ fswz) * 8;
      s8v af[4], bf[4];
#pragma unroll
      for (int i = 0; i < 4; ++i)
        af[i] = *(const s8v*)&Asm[wm + i * 16 + fl][slot];
#pragma unroll
      for (int i = 0; i < 4; ++i)
        bf[i] = *(const s8v*)&Bsm[wn + i * 16 + fl][slot];
#pragma unroll
      for (int mi = 0; mi < 4; ++mi)
#pragma unroll
        for (int ni = 0; ni < 4; ++ni)
          acc[mi][ni] = __builtin_amdgcn_mfma_f32_16x16x32_bf16(af[mi], bf[ni], acc[mi][ni], 0, 0, 0);
    }
    __syncthreads();
  }

#pragma unroll
  for (int mi = 0; mi < 4; ++mi) {
#pragma unroll
    for (int b = 0; b < 4; ++b) {
      int tm = wm + mi * 16 + fh * 4 + b;
      int gm = mbase + tm;
      if (gm < cnt) {
        u16* hrow = hout + (size_t)(off + gm) * N;
#pragma unroll
        for (int ni = 0; ni < 4; ++ni) {
          int n = nbase + wn + ni * 16 + fl;
          float v = acc[mi][ni][b] + bias[e * N + n];
          v = v > 0.f ? v : 0.f;
          hrow[n] = f2bf(v);
        }
      }
    }
  }
}

// ======== GEMM2: out += gate*(h * W2t^T + b2). 256x256 tile, 16 waves, split-K=2
// (kh==0 adds bias; atomicAdd epilogue combines halves — R13-verified), 64KB LDS,
// same proven loop + swizzle + XCD grid. Staged: 1.07 GB.
template<int K, int N, int KSPLIT>
__global__ __launch_bounds__(1024) void moe_gemm2(
    const u16* __restrict__ A, const u16* __restrict__ Bt,
    const float* __restrict__ bias,
    const int* __restrict__ counts, const int* __restrict__ offsets,
    const int* __restrict__ entryTok, const float* __restrict__ entryGate,
    float* __restrict__ out) {
  constexpr int KLEN = K / KSPLIT;      // 2048
  constexpr int NM = TT / 256;          // 32
  constexpr int NX = N / 256;           // 4
  constexpr int nwg = EE * NX * NM * KSPLIT;   // 2048

  const int p = blockIdx.x;
  const int l = (p & 7) * (nwg >> 3) + (p >> 3);
  const int kh = l % KSPLIT;
  int r = l / KSPLIT;
  const int my = r % NM; r /= NM;
  const int nx = r % NX;
  const int e = r / NX;

  const int cnt = counts[e];
  const int mbase = my * 256;
  if (mbase >= cnt) return;
  const int off = offsets[e];
  const int nbase = nx * 256;
  const int k0 = kh * KLEN;
  const int tid = threadIdx.x;
  const int w = tid >> 6, lane = tid & 63;

  __shared__ __align__(16) u16 Asm[256][64];
  __shared__ __align__(16) u16 Bsm[256][64];

  const u16* asrc[2];
  const u16* bsrc[2];
  u32 adst[2], bdst[2];
#pragma unroll
  for (int j = 0; j < 2; ++j) {
    int c = j * 1024 + tid;
    int row = c >> 3;
    int col = ((c & 7) ^ (row & 7)) * 8;
    int gm = mbase + row;
    int mm = (gm < cnt) ? gm : (cnt - 1);
    asrc[j] = A + (size_t)(off + mm) * K + k0 + col;
    adst[j] = (u32)c * 16;
    bsrc[j] = Bt + (size_t)e * N * K + (size_t)(nbase + row) * K + k0 + col;
    bdst[j] = (u32)c * 16;
  }

  const int wm = (w >> 2) * 64, wn = (w & 3) * 64;   // 4m x 4n waves
  const int fl = lane & 15, fh = lane >> 4;
  const int fswz = fl & 7;

  fx4 acc[4][4];
#pragma unroll
  for (int mi = 0; mi < 4; ++mi)
#pragma unroll
    for (int ni = 0; ni < 4; ++ni)
      acc[mi][ni] = (fx4){0.f, 0.f, 0.f, 0.f};

  for (int kt = 0; kt < KLEN; kt += 64) {
#pragma unroll
    for (int j = 0; j < 2; ++j) {
      gl2lds16(asrc[j] + kt, (char*)&Asm[0][0] + adst[j]);
      gl2lds16(bsrc[j] + kt, (char*)&Bsm[0][0] + bdst[j]);
    }
    __syncthreads();
#pragma unroll
    for (int ks = 0; ks < 2; ++ks) {
      const int slot = ((ks * 4 + fh) ^ fswz) * 8;
      s8v af[4], bf[4];
#pragma unroll
      for (int i = 0; i < 4; ++i)
        af[i] = *(const s8v*)&Asm[wm + i * 16 + fl][slot];
#pragma unroll
      for (int i = 0; i < 4; ++i)
        bf[i] = *(const s8v*)&Bsm[wn + i * 16 + fl][slot];
#pragma unroll
      for (int mi = 0; mi < 4; ++mi)
#pragma unroll
        for (int ni = 0; ni < 4; ++ni)
          acc[mi][ni] = __builtin_amdgcn_mfma_f32_16x16x32_bf16(af[mi], bf[ni], acc[mi][ni], 0, 0, 0);
    }
    __syncthreads();
  }

#pragma unroll
  for (int mi = 0; mi < 4; ++mi) {
#pragma unroll
    for (int b = 0; b < 4; ++b) {
      int tm = wm + mi * 16 + fh * 4 + b;
      int gm = mbase + tm;
      if (gm < cnt) {
        int tok = entryTok[off + gm];
        float gate = entryGate[off + gm];
        float* orow = out + (size_t)tok * N;
#pragma unroll
        for (int ni = 0; ni < 4; ++ni) {
          int n = nbase + wn + ni * 16 + fl;
          float v = acc[mi][ni][b] + (kh == 0 ? bias[e * N + n] : 0.f);
          atomicAdd(&orow[n], v * gate);
        }
      }
    }
  }
}

// ======== SLOW GEMM (round-2 proven fallback): B staged from f32 on the fly ========
template<int EPI, int K, int N>
__global__ __launch_bounds__(256) void moe_gemm_slow(
    const u16* __restrict__ A, const float* __restrict__ Bw,
    const float* __restrict__ bias,
    const int* __restrict__ counts, const int* __restrict__ offsets,
    const int* __restrict__ entryTok, const float* __restrict__ entryGate,
    u16* __restrict__ hout, float* __restrict__ out) {
  const int e = blockIdx.z;
  const int cnt = counts[e];
  const int mbase = blockIdx.y * 128;
  if (mbase >= cnt) return;
  const int off = offsets[e];
  const int nbase = blockIdx.x * 128;
  const int tid = threadIdx.x;

  __shared__ u16 Asm[128][72];
  __shared__ u16 Bsm[128][72];
  __shared__ int rowTok[128];
  __shared__ float rowGate[128];

  if (tid < 128) {
    int m = mbase + tid;
    int valid = (m < cnt) ? 1 : 0;
    rowTok[tid] = valid ? entryTok[off + m] : -1;
    rowGate[tid] = valid ? entryGate[off + m] : 0.f;
  }
  __syncthreads();

  const int r = tid >> 1, half = tid & 1;
  const u16* arow;
  if (EPI == 0) {
    int tk = rowTok[r];
    arow = (tk >= 0) ? (A + (size_t)tk * K) : (const u16*)0;
  } else {
    int m = mbase + r;
    arow = (m < cnt) ? (A + (size_t)(off + m) * K) : (const u16*)0;
  }
  const int bk = tid >> 2;
  const int bn0 = (tid & 3) * 32;
  const float* bsrc = Bw + (size_t)e * K * N + (size_t)bk * N + nbase + bn0;

  const int w = tid >> 6, lane = tid & 63;
  const int wm = (w >> 1) * 64, wn = (w & 1) * 64;
  const int fl = lane & 15, fh = lane >> 4;

  fx4 acc[4][4];
#pragma unroll
  for (int mi = 0; mi < 4; ++mi)
#pragma unroll
    for (int ni = 0; ni < 4; ++ni)
      acc[mi][ni] = (fx4){0.f, 0.f, 0.f, 0.f};

  for (int kt = 0; kt < K; kt += 64) {
#pragma unroll
    for (int j = 0; j < 4; ++j) {
      int col = half * 32 + j * 8;
      i4v va = arow ? *(const i4v*)(arow + kt + col) : (i4v){0, 0, 0, 0};
      *(i4v*)&Asm[r][col] = va;
    }
#pragma unroll
    for (int j = 0; j < 8; ++j) {
      float4 v = *(const float4*)(bsrc + (size_t)kt * N + j * 4);
      Bsm[bn0 + j * 4 + 0][bk] = f2bf(v.x);
      Bsm[bn0 + j * 4 + 1][bk] = f2bf(v.y);
      Bsm[bn0 + j * 4 + 2][bk] = f2bf(v.z);
      Bsm[bn0 + j * 4 + 3][bk] = f2bf(v.w);
    }
    __syncthreads();
#pragma unroll
    for (int ks = 0; ks < 2; ++ks) {
      s8v af[4], bf[4];
#pragma unroll
      for (int i = 0; i < 4; ++i)
        af[i] = *(const s8v*)&Asm[wm + i * 16 + fl][ks * 32 + fh * 8];
#pragma unroll
      for (int i = 0; i < 4; ++i)
        bf[i] = *(const s8v*)&Bsm[wn + i * 16 + fl][ks * 32 + fh * 8];
#pragma unroll
      for (int mi = 0; mi < 4; ++mi)
#pragma unroll
        for (int ni = 0; ni < 4; ++ni)
          acc[mi][ni] = __builtin_amdgcn_mfma_f32_16x16x32_bf16(af[mi], bf[ni], acc[mi][ni], 0, 0, 0);
    }
    __syncthreads();
  }

#pragma unroll
  for (int mi = 0; mi < 4; ++mi) {
#pragma unroll
    for (int ni = 0; ni < 4; ++ni) {
      int n = nbase + wn + ni * 16 + fl;
      float bv = bias[e * N + n];
#pragma unroll
      for (int b = 0; b < 4; ++b) {
        int tm = wm + mi * 16 + fh * 4 + b;
        int gm = mbase + tm;
        if (gm < cnt) {
          float v = acc[mi][ni][b] + bv;
          if (EPI == 0) {
            v = v > 0.f ? v : 0.f;
            hout[(size_t)(off + gm) * N + n] = f2bf(v);
          } else {
            atomicAdd(&out[(size_t)rowTok[tm] * N + n], v * rowGate[tm]);
          }
        }
      }
    }
  }
}

extern "C" void kernel_launch(void* const* d_in, const int* in_sizes, int n_in,
                              void* d_out, int out_size, void* d_ws, size_t ws_size,
                              hipStream_t stream) {
  const float* x  = (const float*)d_in[0];
  const float* Wg = (const float*)d_in[1];
  const float* W1 = (const float*)d_in[2];
  const float* b1 = (const float*)d_in[3];
  const float* W2 = (const float*)d_in[4];
  const float* b2 = (const float*)d_in[5];
  float* out = (float*)d_out;

  char* ws = (char*)d_ws;
  int* counts  = (int*)(ws + 0);
  int* offsets = (int*)(ws + 128);
  size_t o = 256;
  int* topIdx = (int*)(ws + o);        o += (size_t)2 * TT * 4;
  float* gates = (float*)(ws + o);     o += (size_t)2 * TT * 4;
  int* entryTok = (int*)(ws + o);      o += (size_t)2 * TT * 4;
  float* entryGate = (float*)(ws + o); o += (size_t)2 * TT * 4;
  u16* xb  = (u16*)(ws + o);           o += (size_t)TT * DD * 2;          // 16.8 MB

  // fast layout: wbuf (shared for w1t then w2t) + hbuf = 218.4 MB total
  const size_t FAST_REQ = (size_t)218366208;
  const bool fast = (ws_size >= FAST_REQ);

  hipMemsetAsync(d_out, 0, (size_t)TT * DD * 4, stream);
  zero_meta<<<1, 64, 0, stream>>>(counts);
  router_kernel<<<TT / 4, 256, 0, stream>>>(x, Wg, topIdx, gates, counts, xb);
  prefix_kernel<<<1, 1, 0, stream>>>(counts, offsets);
  scatter_det<<<EE, 1024, 0, stream>>>(topIdx, gates, offsets, entryTok, entryGate);

  if (fast) {
    u16* wbuf = (u16*)(ws + o);                     // 67.1 MB (w1t, then w2t)
    u16* hbuf = (u16*)(ws + o + (size_t)EE * DD * HH * 2);  // 134.2 MB
    transpose_convert<DD, HH><<<dim3(HH / 64, DD / 64, EE), 256, 0, stream>>>(W1, wbuf);
    // GEMM1: 256x256, 16 waves; 1D grid 8 * 16 * 32 = 4096, XCD-chunked
    moe_gemm1<DD, HH><<<EE * (HH / 256) * (TT / 256), 1024, 0, stream>>>(
        xb, wbuf, b1, counts, offsets, entryTok, hbuf);
    transpose_convert<HH, DD><<<dim3(DD / 64, HH / 64, EE), 256, 0, stream>>>(W2, wbuf);
    // GEMM2: 256x256, 16 waves, split-K=2; 1D grid 8 * 4 * 32 * 2 = 2048, XCD-chunked
    moe_gemm2<HH, DD, 2><<<EE * (DD / 256) * (TT / 256) * 2, 1024, 0, stream>>>(
        hbuf, wbuf, b2, counts, offsets, entryTok, entryGate, out);
  } else {
    u16* hbuf = (u16*)(ws + o);                     // 134.2 MB
    moe_gemm_slow<0, DD, HH><<<dim3(HH / 128, TT / 128, EE), 256, 0, stream>>>(
        xb, W1, b1, counts, offsets, entryTok, entryGate, hbuf, nullptr);
    moe_gemm_slow<1, HH, DD><<<dim3(DD / 128, TT / 128, EE), 256, 0, stream>>>(
        hbuf, W2, b2, counts, offsets, entryTok, entryGate, nullptr, out);
  }
}

// Round 15
// 726.264 us; speedup vs baseline: 1.1362x; 1.1362x over previous
//
#include <hip/hip_runtime.h>
#include <hip/hip_bf16.h>

#define TT 8192
#define DD 1024
#define HH 4096
#define EE 8

typedef unsigned short u16;
typedef unsigned int u32;
typedef float fx4 __attribute__((ext_vector_type(4)));
typedef short s8v __attribute__((ext_vector_type(8)));
typedef int i4v __attribute__((ext_vector_type(4)));
typedef u16 u16x4 __attribute__((ext_vector_type(4)));
typedef u16 u16x8 __attribute__((ext_vector_type(8)));

__device__ __forceinline__ u16 f2bf(float x) {
  union { float f; u32 u; } c; c.f = x;
  u32 r = (c.u + 0x7FFFu + ((c.u >> 16) & 1u)) >> 16;
  return (u16)r;
}

__device__ __forceinline__ void gl2lds16(const void* g, void* l) {
  __builtin_amdgcn_global_load_lds(
      (const __attribute__((address_space(1))) void*)g,
      (__attribute__((address_space(3))) void*)l, 16, 0, 0);
}

// ---------------- meta ----------------
__global__ void zero_meta(int* counts) {
  if (threadIdx.x < EE) counts[threadIdx.x] = 0;
}

// ---------------- transpose + convert W [E][R][C] f32 -> Wt [E][C][R] bf16 ----------------
// 64r x 128c tiles, float4 loads, padded LDS, 16B (8x bf16) stores.
template<int R, int C>
__global__ void transpose_convert(const float* __restrict__ W, u16* __restrict__ Wt) {
  __shared__ float tile[64][129];
  const int e = blockIdx.z;
  const float* We = W + (size_t)e * R * C;
  u16* Wte = Wt + (size_t)e * R * C;
  const int r0 = blockIdx.y * 64, c0 = blockIdx.x * 128;
  const int tid = threadIdx.x;
#pragma unroll
  for (int i = 0; i < 8; ++i) {
    int q = i * 256 + tid;            // 2048 float4 chunks
    int rr = q >> 5;                  // 0..63
    int cc = (q & 31) * 4;            // 0..124
    float4 v = *(const float4*)(We + (size_t)(r0 + rr) * C + c0 + cc);
    tile[rr][cc + 0] = v.x; tile[rr][cc + 1] = v.y;
    tile[rr][cc + 2] = v.z; tile[rr][cc + 3] = v.w;
  }
  __syncthreads();
#pragma unroll
  for (int i = 0; i < 4; ++i) {
    int s = i * 256 + tid;            // 1024 output 16B chunks
    int cc = s >> 3;                  // 0..127
    int rseg = (s & 7) * 8;           // 0..56
    u16x8 o;
#pragma unroll
    for (int j = 0; j < 8; ++j) o[j] = f2bf(tile[rseg + j][cc]);
    *(u16x8*)(Wte + (size_t)(c0 + cc) * R + r0 + rseg) = o;
  }
}

// ---------------- router: logits (f64 acc) + top2 + softmax + histogram + x->bf16 ----------------
__global__ void router_kernel(const float* __restrict__ x, const float* __restrict__ Wg,
                              int* __restrict__ topIdx, float* __restrict__ gates,
                              int* __restrict__ counts, u16* __restrict__ xb) {
  __shared__ float wg[EE][DD + 1];
  const int tid = threadIdx.x;
  for (int i = tid; i < DD * EE; i += 256) wg[i & 7][i >> 3] = Wg[i];
  __syncthreads();
  const int w = tid >> 6, lane = tid & 63;
  const int t = blockIdx.x * 4 + w;
  double acc[EE];
#pragma unroll
  for (int e = 0; e < EE; ++e) acc[e] = 0.0;
  const float* xr = x + (size_t)t * DD;
  u16* xbr = xb + (size_t)t * DD;
  for (int i = 0; i < DD / 64; ++i) {
    int d = i * 64 + lane;
    float xf = xr[d];
    xbr[d] = f2bf(xf);
    double xv = (double)xf;
#pragma unroll
    for (int e = 0; e < EE; ++e) acc[e] += xv * (double)wg[e][d];
  }
#pragma unroll
  for (int e = 0; e < EE; ++e) {
    double v = acc[e];
#pragma unroll
    for (int s = 32; s > 0; s >>= 1) v += __shfl_xor(v, s, 64);
    acc[e] = v;
  }
  if (lane == 0) {
    float v0 = -3.4e38f, v1 = -3.4e38f; int i0 = 0, i1 = 0;
#pragma unroll
    for (int e = 0; e < EE; ++e) {
      float v = (float)acc[e];
      if (v > v0) { v1 = v0; i1 = i0; v0 = v; i0 = e; }
      else if (v > v1) { v1 = v; i1 = e; }
    }
    float ee = expf(v1 - v0);
    float g0 = 1.f / (1.f + ee);
    float g1 = ee / (1.f + ee);
    topIdx[t * 2 + 0] = i0; topIdx[t * 2 + 1] = i1;
    gates[t * 2 + 0] = g0; gates[t * 2 + 1] = g1;
    atomicAdd(&counts[i0], 1);
    atomicAdd(&counts[i1], 1);
  }
}

__global__ void prefix_kernel(const int* __restrict__ counts, int* __restrict__ offsets) {
  if (threadIdx.x == 0) {
    int s = 0;
    for (int e = 0; e < EE; ++e) { offsets[e] = s; s += counts[e]; }
    offsets[EE] = s;
  }
}

// ---------------- deterministic scatter: one block per expert, token-ordered ----------------
__global__ void scatter_det(const int* __restrict__ topIdx, const float* __restrict__ gates,
                            const int* __restrict__ offsets, int* __restrict__ entryTok,
                            float* __restrict__ entryGate) {
  const int e = blockIdx.x;
  const int tid = threadIdx.x;
  const int lane = tid & 63, w = tid >> 6;
  __shared__ int base;
  __shared__ int wsum[16];
  __shared__ int woff[16];
  __shared__ int chunktot;
  if (tid == 0) base = offsets[e];
  __syncthreads();
  for (int t0 = 0; t0 < TT; t0 += 1024) {
    int t = t0 + tid;
    int k = -1;
    if (topIdx[t * 2 + 0] == e) k = 0;
    else if (topIdx[t * 2 + 1] == e) k = 1;
    unsigned long long m = __ballot(k >= 0);
    int pre = __popcll(m & ((1ULL << lane) - 1ULL));
    if (lane == 0) wsum[w] = __popcll(m);
    __syncthreads();
    if (tid == 0) {
      int s = 0;
      for (int i = 0; i < 16; ++i) { woff[i] = s; s += wsum[i]; }
      chunktot = s;
    }
    __syncthreads();
    if (k >= 0) {
      int p = base + woff[w] + pre;
      entryTok[p] = t;
      entryGate[p] = gates[t * 2 + k];
    }
    __syncthreads();
    if (tid == 0) base += chunktot;
    __syncthreads();
  }
}

// ======== GEMM1: h = relu(x_gathered * W1t^T + b1). 128m x 256n tile, BK=64,
// 8 waves (2m x 4n of 64x64 -> acc[4][4]=64), 48KB LDS single-buf, R4-proven
// 2-barrier loop, T2 source-side swizzle, XCD-chunked (e,nx,my-fastest) 1D grid.
// R12-verified: 243 us at the ~6.6 TB/s staging wall (1.61 GB staged).
template<int K, int N>
__global__ __launch_bounds__(512) void moe_gemm1(
    const u16* __restrict__ A, const u16* __restrict__ Bt,
    const float* __restrict__ bias,
    const int* __restrict__ counts, const int* __restrict__ offsets,
    const int* __restrict__ entryTok, u16* __restrict__ hout) {
  constexpr int NM = TT / 128;          // 64
  constexpr int NX = N / 256;           // 16
  constexpr int nwg = EE * NX * NM;     // 8192

  const int p = blockIdx.x;
  const int l = (p & 7) * (nwg >> 3) + (p >> 3);
  const int e = l / (NX * NM);
  const int lr = l % (NX * NM);
  const int nx = lr / NM;
  const int my = lr % NM;

  const int cnt = counts[e];
  const int mbase = my * 128;
  if (mbase >= cnt) return;
  const int off = offsets[e];
  const int nbase = nx * 256;
  const int tid = threadIdx.x;
  const int w = tid >> 6, lane = tid & 63;

  __shared__ __align__(16) u16 Asm[128][64];
  __shared__ __align__(16) u16 Bsm[256][64];

  const u16* asrc[2];
  const u16* bsrc[4];
  u32 adst[2], bdst[4];
#pragma unroll
  for (int j = 0; j < 2; ++j) {
    int c = j * 512 + tid;
    int row = c >> 3;
    int col = ((c & 7) ^ (row & 7)) * 8;
    int gm = mbase + row;
    int mm = (gm < cnt) ? gm : (cnt - 1);
    asrc[j] = A + (size_t)entryTok[off + mm] * K + col;
    adst[j] = (u32)c * 16;
  }
#pragma unroll
  for (int j = 0; j < 4; ++j) {
    int c = j * 512 + tid;
    int row = c >> 3;
    int col = ((c & 7) ^ (row & 7)) * 8;
    bsrc[j] = Bt + (size_t)e * N * K + (size_t)(nbase + row) * K + col;
    bdst[j] = (u32)c * 16;
  }

  const int wm = (w >> 2) * 64, wn = (w & 3) * 64;   // 2m x 4n
  const int fl = lane & 15, fh = lane >> 4;
  const int fswz = fl & 7;

  fx4 acc[4][4];
#pragma unroll
  for (int mi = 0; mi < 4; ++mi)
#pragma unroll
    for (int ni = 0; ni < 4; ++ni)
      acc[mi][ni] = (fx4){0.f, 0.f, 0.f, 0.f};

  for (int kt = 0; kt < K; kt += 64) {
#pragma unroll
    for (int j = 0; j < 2; ++j)
      gl2lds16(asrc[j] + kt, (char*)&Asm[0][0] + adst[j]);
#pragma unroll
    for (int j = 0; j < 4; ++j)
      gl2lds16(bsrc[j] + kt, (char*)&Bsm[0][0] + bdst[j]);
    __syncthreads();
#pragma unroll
    for (int ks = 0; ks < 2; ++ks) {
      const int slot = ((ks * 4 + fh) ^ fswz) * 8;
      s8v af[4], bf[4];
#pragma unroll
      for (int i = 0; i < 4; ++i)
        af[i] = *(const s8v*)&Asm[wm + i * 16 + fl][slot];
#pragma unroll
      for (int i = 0; i < 4; ++i)
        bf[i] = *(const s8v*)&Bsm[wn + i * 16 + fl][slot];
#pragma unroll
      for (int mi = 0; mi < 4; ++mi)
#pragma unroll
        for (int ni = 0; ni < 4; ++ni)
          acc[mi][ni] = __builtin_amdgcn_mfma_f32_16x16x32_bf16(af[mi], bf[ni], acc[mi][ni], 0, 0, 0);
    }
    __syncthreads();
  }

#pragma unroll
  for (int mi = 0; mi < 4; ++mi) {
#pragma unroll
    for (int b = 0; b < 4; ++b) {
      int tm = wm + mi * 16 + fh * 4 + b;
      int gm = mbase + tm;
      if (gm < cnt) {
        u16* hrow = hout + (size_t)(off + gm) * N;
#pragma unroll
        for (int ni = 0; ni < 4; ++ni) {
          int n = nbase + wn + ni * 16 + fl;
          float v = acc[mi][ni][b] + bias[e * N + n];
          v = v > 0.f ? v : 0.f;
          hrow[n] = f2bf(v);
        }
      }
    }
  }
}

// ======== GEMM2: out += gate*(h * W2t^T + b2). 256m x 128n tile, BK=64,
// 8 waves (4m x 2n of 64x64), 48KB LDS, same proven loop + swizzle + XCD grid.
// R12-verified: 291 us (1.61 GB staged).
template<int K, int N>
__global__ __launch_bounds__(512) void moe_gemm2(
    const u16* __restrict__ A, const u16* __restrict__ Bt,
    const float* __restrict__ bias,
    const int* __restrict__ counts, const int* __restrict__ offsets,
    const int* __restrict__ entryTok, const float* __restrict__ entryGate,
    float* __restrict__ out) {
  constexpr int NM = TT / 256;          // 32
  constexpr int NX = N / 128;           // 8
  constexpr int nwg = EE * NX * NM;     // 2048

  const int p = blockIdx.x;
  const int l = (p & 7) * (nwg >> 3) + (p >> 3);
  const int e = l / (NX * NM);
  const int lr = l % (NX * NM);
  const int nx = lr / NM;
  const int my = lr % NM;

  const int cnt = counts[e];
  const int mbase = my * 256;
  if (mbase >= cnt) return;
  const int off = offsets[e];
  const int nbase = nx * 128;
  const int tid = threadIdx.x;
  const int w = tid >> 6, lane = tid & 63;

  __shared__ __align__(16) u16 Asm[256][64];
  __shared__ __align__(16) u16 Bsm[128][64];

  const u16* asrc[4];
  const u16* bsrc[2];
  u32 adst[4], bdst[2];
#pragma unroll
  for (int j = 0; j < 4; ++j) {
    int c = j * 512 + tid;
    int row = c >> 3;
    int col = ((c & 7) ^ (row & 7)) * 8;
    int gm = mbase + row;
    int mm = (gm < cnt) ? gm : (cnt - 1);
    asrc[j] = A + (size_t)(off + mm) * K + col;
    adst[j] = (u32)c * 16;
  }
#pragma unroll
  for (int j = 0; j < 2; ++j) {
    int c = j * 512 + tid;
    int row = c >> 3;
    int col = ((c & 7) ^ (row & 7)) * 8;
    bsrc[j] = Bt + (size_t)e * N * K + (size_t)(nbase + row) * K + col;
    bdst[j] = (u32)c * 16;
  }

  const int wm = (w >> 1) * 64, wn = (w & 1) * 64;   // 4m x 2n
  const int fl = lane & 15, fh = lane >> 4;
  const int fswz = fl & 7;

  fx4 acc[4][4];
#pragma unroll
  for (int mi = 0; mi < 4; ++mi)
#pragma unroll
    for (int ni = 0; ni < 4; ++ni)
      acc[mi][ni] = (fx4){0.f, 0.f, 0.f, 0.f};

  for (int kt = 0; kt < K; kt += 64) {
#pragma unroll
    for (int j = 0; j < 4; ++j)
      gl2lds16(asrc[j] + kt, (char*)&Asm[0][0] + adst[j]);
#pragma unroll
    for (int j = 0; j < 2; ++j)
      gl2lds16(bsrc[j] + kt, (char*)&Bsm[0][0] + bdst[j]);
    __syncthreads();
#pragma unroll
    for (int ks = 0; ks < 2; ++ks) {
      const int slot = ((ks * 4 + fh) ^ fswz) * 8;
      s8v af[4], bf[4];
#pragma unroll
      for (int i = 0; i < 4; ++i)
        af[i] = *(const s8v*)&Asm[wm + i * 16 + fl][slot];
#pragma unroll
      for (int i = 0; i < 4; ++i)
        bf[i] = *(const s8v*)&Bsm[wn + i * 16 + fl][slot];
#pragma unroll
      for (int mi = 0; mi < 4; ++mi)
#pragma unroll
        for (int ni = 0; ni < 4; ++ni)
          acc[mi][ni] = __builtin_amdgcn_mfma_f32_16x16x32_bf16(af[mi], bf[ni], acc[mi][ni], 0, 0, 0);
    }
    __syncthreads();
  }

#pragma unroll
  for (int mi = 0; mi < 4; ++mi) {
#pragma unroll
    for (int b = 0; b < 4; ++b) {
      int tm = wm + mi * 16 + fh * 4 + b;
      int gm = mbase + tm;
      if (gm < cnt) {
        int tok = entryTok[off + gm];
        float gate = entryGate[off + gm];
        float* orow = out + (size_t)tok * N;
#pragma unroll
        for (int ni = 0; ni < 4; ++ni) {
          int n = nbase + wn + ni * 16 + fl;
          float v = acc[mi][ni][b] + bias[e * N + n];
          atomicAdd(&orow[n], v * gate);
        }
      }
    }
  }
}

// ======== SLOW GEMM (round-2 proven fallback): B staged from f32 on the fly ========
template<int EPI, int K, int N>
__global__ __launch_bounds__(256) void moe_gemm_slow(
    const u16* __restrict__ A, const float* __restrict__ Bw,
    const float* __restrict__ bias,
    const int* __restrict__ counts, const int* __restrict__ offsets,
    const int* __restrict__ entryTok, const float* __restrict__ entryGate,
    u16* __restrict__ hout, float* __restrict__ out) {
  const int e = blockIdx.z;
  const int cnt = counts[e];
  const int mbase = blockIdx.y * 128;
  if (mbase >= cnt) return;
  const int off = offsets[e];
  const int nbase = blockIdx.x * 128;
  const int tid = threadIdx.x;

  __shared__ u16 Asm[128][72];
  __shared__ u16 Bsm[128][72];
  __shared__ int rowTok[128];
  __shared__ float rowGate[128];

  if (tid < 128) {
    int m = mbase + tid;
    int valid = (m < cnt) ? 1 : 0;
    rowTok[tid] = valid ? entryTok[off + m] : -1;
    rowGate[tid] = valid ? entryGate[off + m] : 0.f;
  }
  __syncthreads();

  const int r = tid >> 1, half = tid & 1;
  const u16* arow;
  if (EPI == 0) {
    int tk = rowTok[r];
    arow = (tk >= 0) ? (A + (size_t)tk * K) : (const u16*)0;
  } else {
    int m = mbase + r;
    arow = (m < cnt) ? (A + (size_t)(off + m) * K) : (const u16*)0;
  }
  const int bk = tid >> 2;
  const int bn0 = (tid & 3) * 32;
  const float* bsrc = Bw + (size_t)e * K * N + (size_t)bk * N + nbase + bn0;

  const int w = tid >> 6, lane = tid & 63;
  const int wm = (w >> 1) * 64, wn = (w & 1) * 64;
  const int fl = lane & 15, fh = lane >> 4;

  fx4 acc[4][4];
#pragma unroll
  for (int mi = 0; mi < 4; ++mi)
#pragma unroll
    for (int ni = 0; ni < 4; ++ni)
      acc[mi][ni] = (fx4){0.f, 0.f, 0.f, 0.f};

  for (int kt = 0; kt < K; kt += 64) {
#pragma unroll
    for (int j = 0; j < 4; ++j) {
      int col = half * 32 + j * 8;
      i4v va = arow ? *(const i4v*)(arow + kt + col) : (i4v){0, 0, 0, 0};
      *(i4v*)&Asm[r][col] = va;
    }
#pragma unroll
    for (int j = 0; j < 8; ++j) {
      float4 v = *(const float4*)(bsrc + (size_t)kt * N + j * 4);
      Bsm[bn0 + j * 4 + 0][bk] = f2bf(v.x);
      Bsm[bn0 + j * 4 + 1][bk] = f2bf(v.y);
      Bsm[bn0 + j * 4 + 2][bk] = f2bf(v.z);
      Bsm[bn0 + j * 4 + 3][bk] = f2bf(v.w);
    }
    __syncthreads();
#pragma unroll
    for (int ks = 0; ks < 2; ++ks) {
      s8v af[4], bf[4];
#pragma unroll
      for (int i = 0; i < 4; ++i)
        af[i] = *(const s8v*)&Asm[wm + i * 16 + fl][ks * 32 + fh * 8];
#pragma unroll
      for (int i = 0; i < 4; ++i)
        bf[i] = *(const s8v*)&Bsm[wn + i * 16 + fl][ks * 32 + fh * 8];
#pragma unroll
      for (int mi = 0; mi < 4; ++mi)
#pragma unroll
        for (int ni = 0; ni < 4; ++ni)
          acc[mi][ni] = __builtin_amdgcn_mfma_f32_16x16x32_bf16(af[mi], bf[ni], acc[mi][ni], 0, 0, 0);
    }
    __syncthreads();
  }

#pragma unroll
  for (int mi = 0; mi < 4; ++mi) {
#pragma unroll
    for (int ni = 0; ni < 4; ++ni) {
      int n = nbase + wn + ni * 16 + fl;
      float bv = bias[e * N + n];
#pragma unroll
      for (int b = 0; b < 4; ++b) {
        int tm = wm + mi * 16 + fh * 4 + b;
        int gm = mbase + tm;
        if (gm < cnt) {
          float v = acc[mi][ni][b] + bv;
          if (EPI == 0) {
            v = v > 0.f ? v : 0.f;
            hout[(size_t)(off + gm) * N + n] = f2bf(v);
          } else {
            atomicAdd(&out[(size_t)rowTok[tm] * N + n], v * rowGate[tm]);
          }
        }
      }
    }
  }
}

extern "C" void kernel_launch(void* const* d_in, const int* in_sizes, int n_in,
                              void* d_out, int out_size, void* d_ws, size_t ws_size,
                              hipStream_t stream) {
  const float* x  = (const float*)d_in[0];
  const float* Wg = (const float*)d_in[1];
  const float* W1 = (const float*)d_in[2];
  const float* b1 = (const float*)d_in[3];
  const float* W2 = (const float*)d_in[4];
  const float* b2 = (const float*)d_in[5];
  float* out = (float*)d_out;

  char* ws = (char*)d_ws;
  int* counts  = (int*)(ws + 0);
  int* offsets = (int*)(ws + 128);
  size_t o = 256;
  int* topIdx = (int*)(ws + o);        o += (size_t)2 * TT * 4;
  float* gates = (float*)(ws + o);     o += (size_t)2 * TT * 4;
  int* entryTok = (int*)(ws + o);      o += (size_t)2 * TT * 4;
  float* entryGate = (float*)(ws + o); o += (size_t)2 * TT * 4;
  u16* xb  = (u16*)(ws + o);           o += (size_t)TT * DD * 2;          // 16.8 MB

  // fast layout: wbuf (shared for w1t then w2t) + hbuf = 218.4 MB total
  const size_t FAST_REQ = (size_t)218366208;
  const bool fast = (ws_size >= FAST_REQ);

  hipMemsetAsync(d_out, 0, (size_t)TT * DD * 4, stream);
  zero_meta<<<1, 64, 0, stream>>>(counts);
  router_kernel<<<TT / 4, 256, 0, stream>>>(x, Wg, topIdx, gates, counts, xb);
  prefix_kernel<<<1, 1, 0, stream>>>(counts, offsets);
  scatter_det<<<EE, 1024, 0, stream>>>(topIdx, gates, offsets, entryTok, entryGate);

  if (fast) {
    u16* wbuf = (u16*)(ws + o);                     // 67.1 MB (w1t, then w2t)
    u16* hbuf = (u16*)(ws + o + (size_t)EE * DD * HH * 2);  // 134.2 MB
    transpose_convert<DD, HH><<<dim3(HH / 128, DD / 64, EE), 256, 0, stream>>>(W1, wbuf);
    // GEMM1: 128m x 256n; 1D grid 8 * 16 * 64 = 8192, XCD-chunked
    moe_gemm1<DD, HH><<<EE * (HH / 256) * (TT / 128), 512, 0, stream>>>(
        xb, wbuf, b1, counts, offsets, entryTok, hbuf);
    transpose_convert<HH, DD><<<dim3(DD / 128, HH / 64, EE), 256, 0, stream>>>(W2, wbuf);
    // GEMM2: 256m x 128n; 1D grid 8 * 8 * 32 = 2048, XCD-chunked
    moe_gemm2<HH, DD><<<EE * (DD / 128) * (TT / 256), 512, 0, stream>>>(
        hbuf, wbuf, b2, counts, offsets, entryTok, entryGate, out);
  } else {
    u16* hbuf = (u16*)(ws + o);                     // 134.2 MB
    moe_gemm_slow<0, DD, HH><<<dim3(HH / 128, TT / 128, EE), 256, 0, stream>>>(
        xb, W1, b1, counts, offsets, entryTok, entryGate, hbuf, nullptr);
    moe_gemm_slow<1, HH, DD><<<dim3(DD / 128, TT / 128, EE), 256, 0, stream>>>(
        hbuf, W2, b2, counts, offsets, entryTok, entryGate, nullptr, out);
  }
}